// Round 1
// baseline (1947.907 us; speedup 1.0000x reference)
//
#include <hip/hip_runtime.h>
#include <hip/hip_bf16.h>

#define DI __device__ __forceinline__

DI float fmulr(float a, float b){ return __fmul_rn(a,b); }
DI float faddr(float a, float b){ return __fadd_rn(a,b); }
DI float fsubr(float a, float b){ return __fsub_rn(a,b); }
DI float dist2e(float x,float y,float z,float cx,float cy,float cz){
  float dx=fsubr(x,cx), dy=fsubr(y,cy), dz=fsubr(z,cz);
  return faddr(faddr(fmulr(dx,dx),fmulr(dy,dy)),fmulr(dz,dz));
}

// ---------------- FPS: 8 blocks (one per batch), 1024 threads, all-LDS ----------------
__global__ __launch_bounds__(1024) void fps_kernel(const float* __restrict__ xyz, float* __restrict__ out0){
  __shared__ float sx[4096], sy[4096], sz[4096];
  __shared__ float redV[16]; __shared__ int redI[16]; __shared__ int curLds;
  int b = blockIdx.x, tid = threadIdx.x;
  const float* xb = xyz + (size_t)b*4096*3;
  for (int i=0;i<12;i++){ int e=i*1024+tid; float v=xb[e]; int p=e/3, c=e-p*3;
    if(c==0) sx[p]=v; else if(c==1) sy[p]=v; else sz[p]=v; }
  __syncthreads();
  float px[4],py[4],pz[4],dist[4];
  #pragma unroll
  for(int j=0;j<4;j++){int p=tid+j*1024; px[j]=sx[p];py[j]=sy[p];pz[j]=sz[p];dist[j]=1e10f;}
  int cur=0;
  float* ob = out0 + (size_t)b*1024*3;
  for(int t=0;t<1024;t++){
    float cx=sx[cur],cy=sy[cur],cz=sz[cur];
    if(tid==0){ ob[t*3]=cx; ob[t*3+1]=cy; ob[t*3+2]=cz; }
    float bv=-1.0f; int bi=0x7fffffff;
    #pragma unroll
    for(int j=0;j<4;j++){
      float d=dist2e(px[j],py[j],pz[j],cx,cy,cz);
      float nd=fminf(dist[j],d); dist[j]=nd;
      if(nd>bv){bv=nd;bi=tid+j*1024;}
    }
    // intra-wave argmax, tie -> lower index (matches numpy first-occurrence)
    #pragma unroll
    for(int m=32;m>=1;m>>=1){
      float ov=__shfl_xor(bv,m); int oi=__shfl_xor(bi,m);
      if(ov>bv || (ov==bv && oi<bi)){bv=ov;bi=oi;}
    }
    int w = tid>>6;
    if((tid&63)==0){ redV[w]=bv; redI[w]=bi; }
    __syncthreads();
    if(tid<64){
      float v2 = (tid<16)? redV[tid] : -1.0f;
      int   i2 = (tid<16)? redI[tid] : 0x7fffffff;
      #pragma unroll
      for(int m=8;m>=1;m>>=1){
        float ov=__shfl_xor(v2,m); int oi=__shfl_xor(i2,m);
        if(ov>v2 || (ov==v2 && oi<i2)){v2=ov;i2=oi;}
      }
      if(tid==0) curLds=i2;
    }
    __syncthreads();
    cur=curLds;
  }
}

// ---------------- ball query: 1 wave per center ----------------
__global__ __launch_bounds__(256) void ballq_kernel(const float* __restrict__ xyz, const float* __restrict__ out0,
        int* __restrict__ idxw, float* __restrict__ out2){
  int g = blockIdx.x*4 + (threadIdx.x>>6);
  int lane = threadIdx.x&63;
  int b = g>>10;
  const float* xb = xyz + (size_t)b*4096*3;
  float cx=out0[(size_t)g*3], cy=out0[(size_t)g*3+1], cz=out0[(size_t)g*3+2];
  const float R2 = (float)(0.2*0.2);
  int cnt=0, firstp=0; bool haveFirst=false;
  for(int c=0;c<64;c++){
    int p=c*64+lane;
    float x=xb[p*3], y=xb[p*3+1], z=xb[p*3+2];
    float d2=dist2e(x,y,z,cx,cy,cz);
    bool inb = d2 < R2;
    unsigned long long mask=__ballot(inb);
    if(!haveFirst && mask){ firstp = c*64 + (__ffsll((unsigned long long)mask)-1); haveFirst=true; }
    int pos = cnt + (int)__popcll(mask & ((1ull<<lane)-1ull));
    if(inb && pos<32){ idxw[(size_t)g*32+pos]=p; out2[(size_t)g*32+pos]=(float)p; }
    cnt += (int)__popcll(mask);
    if(cnt>=32) break;
  }
  if(cnt<32){
    for(int j=cnt+lane; j<32; j+=64){ idxw[(size_t)g*32+j]=firstp; out2[(size_t)g*32+j]=(float)firstp; }
  }
}

// ---------------- M = Wq * Wk^T  (3x128) ----------------
__global__ void m_kernel(const float* __restrict__ Wq, const float* __restrict__ Wk, float* __restrict__ M){
  int c = threadIdx.x; // 128
  float m0=0.f,m1=0.f,m2=0.f;
  for(int d=0; d<128; d++){
    float wk = Wk[c*128+d];
    m0 += Wq[d]*wk; m1 += Wq[128+d]*wk; m2 += Wq[256+d]*wk;
  }
  M[c]=m0; M[128+c]=m1; M[256+c]=m2;
}

// ---------------- layer0: gather + (67->64) matmul + bias + partial stats ----------------
__global__ __launch_bounds__(256) void l0_kernel(const float* __restrict__ xyz, const float* __restrict__ pts,
    const float* __restrict__ out0, const int* __restrict__ idxw,
    const float* __restrict__ W0, const float* __restrict__ b0,
    __hip_bfloat16* __restrict__ y0, float* __restrict__ P){
  __shared__ float xl[64*69];
  __shared__ float wl[67*64];
  int tid=threadIdx.x; int base=blockIdx.x*64;
  for(int e=tid; e<67*64; e+=256) wl[e]=W0[e];
  int w=tid>>6, lane=tid&63;
  for(int i=0;i<16;i++){
    int r=w*16+i; int R=base+r;
    int g=R>>5; int b=g>>10; int p=idxw[R];
    const float* prow = pts + ((size_t)b*4096 + (size_t)p)*64;
    xl[r*69+3+lane] = prow[lane];
    if(lane<3){
      xl[r*69+lane] = fsubr(xyz[((size_t)b*4096+(size_t)p)*3+lane], out0[(size_t)g*3+lane]);
    }
  }
  __syncthreads();
  int r=tid&63, cg=tid>>6;
  float acc[16];
  #pragma unroll
  for(int j=0;j<16;j++) acc[j]=b0[cg*16+j];
  for(int c=0;c<67;c++){
    float xv=xl[r*69+c];
    #pragma unroll
    for(int j=0;j<16;j++) acc[j] += xv*wl[c*64+cg*16+j];
  }
  size_t R=(size_t)base+r;
  #pragma unroll
  for(int j=0;j<16;j++) y0[R*64+cg*16+j]=__float2bfloat16(acc[j]);
  #pragma unroll
  for(int j=0;j<16;j++){
    float s=acc[j], q=acc[j]*acc[j];
    #pragma unroll
    for(int m=32;m>=1;m>>=1){ s+=__shfl_xor(s,m); q+=__shfl_xor(q,m); }
    if(r==0){ P[(size_t)blockIdx.x*256 + cg*16+j]=s; P[(size_t)blockIdx.x*256+128+cg*16+j]=q; }
  }
}

// ---------------- mid layers: bn(prev)+relu on load, matmul, bias, partial stats ----------------
template<int CINc,int COUTc>
__global__ __launch_bounds__(256) void lmid_kernel(const __hip_bfloat16* __restrict__ xin,
    const float* __restrict__ ssIn, const float* __restrict__ W, const float* __restrict__ bias,
    __hip_bfloat16* __restrict__ yout, float* __restrict__ P){
  constexpr int STR=CINc+1;
  constexpr int PER=COUTc/4;
  __shared__ float xl[64*STR];
  __shared__ float wl[CINc*COUTc];
  int tid=threadIdx.x; size_t base=(size_t)blockIdx.x*64;
  for(int e=tid;e<CINc*COUTc;e+=256) wl[e]=W[e];
  for(int e=tid;e<64*CINc;e+=256){
    int r=e/CINc, ch=e-r*CINc;
    float v=__bfloat162float(xin[(base+(size_t)r)*CINc+ch]);
    v = v*ssIn[ch]+ssIn[128+ch];
    xl[r*STR+ch]= v>0.f? v:0.f;
  }
  __syncthreads();
  int r=tid&63, cg=tid>>6;
  float acc[PER];
  #pragma unroll
  for(int j=0;j<PER;j++) acc[j]=bias[cg*PER+j];
  for(int c=0;c<CINc;c++){
    float xv=xl[r*STR+c];
    #pragma unroll
    for(int j=0;j<PER;j++) acc[j]+=xv*wl[c*COUTc+cg*PER+j];
  }
  size_t R=base+r;
  #pragma unroll
  for(int j=0;j<PER;j++) yout[R*COUTc+cg*PER+j]=__float2bfloat16(acc[j]);
  #pragma unroll
  for(int j=0;j<PER;j++){
    float s=acc[j],q=acc[j]*acc[j];
    #pragma unroll
    for(int m=32;m>=1;m>>=1){s+=__shfl_xor(s,m);q+=__shfl_xor(q,m);}
    if(r==0){P[(size_t)blockIdx.x*256+cg*PER+j]=s;P[(size_t)blockIdx.x*256+128+cg*PER+j]=q;}
  }
}

// ---------------- finalize stats: scale/shift per channel ----------------
__global__ void fin_kernel(const float* __restrict__ P, const float* __restrict__ gg, const float* __restrict__ be,
                           float* __restrict__ ss){
  int ch=blockIdx.x; int lane=threadIdx.x;
  float s=0.f,q=0.f;
  for(int blk=lane; blk<4096; blk+=64){ s+=P[(size_t)blk*256+ch]; q+=P[(size_t)blk*256+128+ch]; }
  #pragma unroll
  for(int m=32;m>=1;m>>=1){ s+=__shfl_xor(s,m); q+=__shfl_xor(q,m); }
  if(lane==0){
    const float invNT = 1.0f/262144.0f;
    float mean=s*invNT; float var=q*invNT - mean*mean;
    float scale=gg[ch]/sqrtf(var+1e-3f);
    ss[ch]=scale; ss[128+ch]=be[ch]-mean*scale;
  }
}

// ---------------- U = centers @ M ----------------
__global__ void u_kernel(const float* __restrict__ out0, const float* __restrict__ M, float* __restrict__ U){
  int t=blockIdx.x*256+threadIdx.x;
  int g=t>>7, c=t&127;
  float cx=out0[(size_t)g*3],cy=out0[(size_t)g*3+1],cz=out0[(size_t)g*3+2];
  U[t]=cx*M[c]+cy*M[128+c]+cz*M[256+c];
}

// ---------------- per-group: bn2+relu, scores, softmax, hbar ----------------
__global__ __launch_bounds__(256) void sh_kernel(const __hip_bfloat16* __restrict__ y2,
    const float* __restrict__ ss2, const float* __restrict__ U, float* __restrict__ hbar){
  __shared__ float h[2][32*130];
  __shared__ float uLds[2][128];
  __shared__ float sLds[2][32];
  int tid=threadIdx.x; int grp=tid>>7, t=tid&127;
  size_t g=(size_t)blockIdx.x*2+grp;
  for(int i=0;i<32;i++){
    int e=t+i*128; int row=e>>7, ch=e&127;
    float v=__bfloat162float(y2[(g*32+row)*128+ch]);
    v=v*ss2[ch]+ss2[128+ch];
    h[grp][row*130+ch]= v>0.f?v:0.f;
  }
  uLds[grp][t]=U[g*128+t];
  __syncthreads();
  if(t<32){
    float sc=0.f;
    for(int c=0;c<128;c++) sc+=h[grp][t*130+c]*uLds[grp][c];
    sc*=0.08838834764831845f; // 1/sqrt(128)
    float mx=sc;
    #pragma unroll
    for(int m=16;m>=1;m>>=1) mx=fmaxf(mx,__shfl_xor(mx,m));
    float p=expf(sc-mx);
    float sum=p;
    #pragma unroll
    for(int m=16;m>=1;m>>=1) sum+=__shfl_xor(sum,m);
    sLds[grp][t]=p/sum;
  }
  __syncthreads();
  float hb=0.f;
  for(int k=0;k<32;k++) hb+=sLds[grp][k]*h[grp][k*130+t];
  hbar[g*128+t]=hb;
}

// ---------------- pooled = hbar @ Wv ----------------
__global__ __launch_bounds__(256) void pool_kernel(const float* __restrict__ hbar, const float* __restrict__ Wv,
    float* __restrict__ out1){
  __shared__ float wv[32*128];
  __shared__ float xl[32*129];
  int tid=threadIdx.x; size_t g0=(size_t)blockIdx.x*32;
  for(int e=tid;e<32*128;e+=256){ int r=e>>7,ch=e&127; xl[r*129+ch]=hbar[(g0+(size_t)r)*128+ch]; }
  int r=tid&31, cg=tid>>5;
  float acc[16];
  #pragma unroll
  for(int j=0;j<16;j++) acc[j]=0.f;
  for(int cc=0;cc<4;cc++){
    __syncthreads();
    for(int e=tid;e<32*128;e+=256) wv[e]=Wv[cc*32*128+e];
    __syncthreads();
    for(int c=0;c<32;c++){
      float xv=xl[r*129+cc*32+c];
      #pragma unroll
      for(int j=0;j<16;j++) acc[j]+=xv*wv[c*128+cg*16+j];
    }
  }
  #pragma unroll
  for(int j=0;j<16;j++) out1[(g0+(size_t)r)*128+cg*16+j]=acc[j];
}

extern "C" void kernel_launch(void* const* d_in, const int* in_sizes, int n_in,
                              void* d_out, int out_size, void* d_ws, size_t ws_size,
                              hipStream_t stream){
  (void)in_sizes; (void)n_in; (void)out_size; (void)ws_size;
  const float* xyz=(const float*)d_in[0];
  const float* pts=(const float*)d_in[1];
  const float* W0=(const float*)d_in[2];  const float* b0=(const float*)d_in[3];
  const float* g0=(const float*)d_in[4];  const float* be0=(const float*)d_in[5];
  const float* W1=(const float*)d_in[6];  const float* b1=(const float*)d_in[7];
  const float* g1=(const float*)d_in[8];  const float* be1=(const float*)d_in[9];
  const float* W2=(const float*)d_in[10]; const float* b2=(const float*)d_in[11];
  const float* g2=(const float*)d_in[12]; const float* be2=(const float*)d_in[13];
  const float* Wq=(const float*)d_in[14]; const float* Wk=(const float*)d_in[15];
  const float* Wv=(const float*)d_in[16];
  float* out0=(float*)d_out;
  float* out1=out0 + (size_t)8*1024*3;
  float* out2=out1 + (size_t)8192*128;

  char* ws=(char*)d_ws; size_t off=0;
  int* idxw=(int*)(ws+off);                    off += (size_t)8192*32*4;
  __hip_bfloat16* fa=(__hip_bfloat16*)(ws+off); off += (size_t)262144*64*2;
  __hip_bfloat16* fb=(__hip_bfloat16*)(ws+off); off += (size_t)262144*64*2;
  __hip_bfloat16* fc=(__hip_bfloat16*)(ws+off); off += (size_t)262144*128*2;
  float* P =(float*)(ws+off);                  off += (size_t)4096*256*4;
  float* ss0=(float*)(ws+off);                 off += 256*4;
  float* ss1=(float*)(ws+off);                 off += 256*4;
  float* ss2=(float*)(ws+off);                 off += 256*4;
  float* M =(float*)(ws+off);                  off += 3*128*4 + 128; // pad
  float* U =(float*)(ws+off);                  off += (size_t)8192*128*4;
  float* hb=(float*)(ws+off);                  off += (size_t)8192*128*4;

  hipLaunchKernelGGL(fps_kernel,   dim3(8),    dim3(1024), 0, stream, xyz, out0);
  hipLaunchKernelGGL(ballq_kernel, dim3(2048), dim3(256),  0, stream, xyz, out0, idxw, out2);
  hipLaunchKernelGGL(m_kernel,     dim3(1),    dim3(128),  0, stream, Wq, Wk, M);
  hipLaunchKernelGGL(l0_kernel,    dim3(4096), dim3(256),  0, stream, xyz, pts, out0, idxw, W0, b0, fa, P);
  hipLaunchKernelGGL(fin_kernel,   dim3(64),   dim3(64),   0, stream, P, g0, be0, ss0);
  hipLaunchKernelGGL((lmid_kernel<64,64>),  dim3(4096), dim3(256), 0, stream, fa, ss0, W1, b1, fb, P);
  hipLaunchKernelGGL(fin_kernel,   dim3(64),   dim3(64),   0, stream, P, g1, be1, ss1);
  hipLaunchKernelGGL((lmid_kernel<64,128>), dim3(4096), dim3(256), 0, stream, fb, ss1, W2, b2, fc, P);
  hipLaunchKernelGGL(fin_kernel,   dim3(128),  dim3(64),   0, stream, P, g2, be2, ss2);
  hipLaunchKernelGGL(u_kernel,     dim3(4096), dim3(256),  0, stream, out0, M, U);
  hipLaunchKernelGGL(sh_kernel,    dim3(4096), dim3(256),  0, stream, fc, ss2, U, hb);
  hipLaunchKernelGGL(pool_kernel,  dim3(256),  dim3(256),  0, stream, hb, Wv, out1);
}

// Round 2
// 1406.516 us; speedup vs baseline: 1.3849x; 1.3849x over previous
//
#include <hip/hip_runtime.h>
#include <hip/hip_bf16.h>

#define DI __device__ __forceinline__

DI float fmulr(float a, float b){ return __fmul_rn(a,b); }
DI float faddr(float a, float b){ return __fadd_rn(a,b); }
DI float fsubr(float a, float b){ return __fsub_rn(a,b); }
DI float dist2e(float x,float y,float z,float cx,float cy,float cz){
  float dx=fsubr(x,cx), dy=fsubr(y,cy), dz=fsubr(z,cz);
  return faddr(faddr(fmulr(dx,dx),fmulr(dy,dy)),fmulr(dz,dz));
}
DI unsigned short f2bf(float f){ __hip_bfloat16 h=__float2bfloat16(f); return *reinterpret_cast<unsigned short*>(&h); }

// ---------------- FPS: 8 blocks (one per batch), 512 threads, 1 barrier/iter ----------------
__global__ __launch_bounds__(512) void fps_kernel(const float* __restrict__ xyz, float* __restrict__ out0){
  __shared__ float sp[12288];
  __shared__ unsigned long long slots[2][8];
  int b=blockIdx.x, tid=threadIdx.x;
  const float* xb = xyz + (size_t)b*4096*3;
  const float4* src=(const float4*)xb; float4* dst=(float4*)sp;
  #pragma unroll
  for(int i=0;i<6;i++) dst[i*512+tid]=src[i*512+tid];
  __syncthreads();
  float px[8],py[8],pz[8],dist[8];
  #pragma unroll
  for(int j=0;j<8;j++){ int p=tid+j*512; px[j]=sp[3*p]; py[j]=sp[3*p+1]; pz[j]=sp[3*p+2]; dist[j]=1e10f; }
  float cx=sp[0], cy=sp[1], cz=sp[2];
  int w=tid>>6, lane=tid&63;
  float* ob = out0 + (size_t)b*1024*3;
  for(int t=0;t<1024;t++){
    if(tid==0){ ob[t*3]=cx; ob[t*3+1]=cy; ob[t*3+2]=cz; }
    float bv=-1.0f; int bi=0;
    #pragma unroll
    for(int j=0;j<8;j++){
      float d=dist2e(px[j],py[j],pz[j],cx,cy,cz);
      float nd=fminf(dist[j],d); dist[j]=nd;
      if(nd>bv){ bv=nd; bi=tid+j*512; }
    }
    #pragma unroll
    for(int m=32;m>=1;m>>=1){
      float ov=__shfl_xor(bv,m); int oi=__shfl_xor(bi,m);
      if(ov>bv || (ov==bv && oi<bi)){ bv=ov; bi=oi; }
    }
    if(lane==0) slots[t&1][w] = ((unsigned long long)__float_as_uint(bv)<<32) | (unsigned long long)(0xFFFFFFFFu-(unsigned)bi);
    __syncthreads();
    unsigned long long k = slots[t&1][0];
    #pragma unroll
    for(int j=1;j<8;j++){ unsigned long long ok=slots[t&1][j]; if(ok>k) k=ok; }
    int cur = (int)(0xFFFFFFFFu - (unsigned)(k & 0xFFFFFFFFull));
    cx=sp[3*cur]; cy=sp[3*cur+1]; cz=sp[3*cur+2];
  }
}

// ---------------- ball query: 4 waves/block share one batch staged in LDS ----------------
__global__ __launch_bounds__(256) void ballq_kernel(const float* __restrict__ xyz, const float* __restrict__ out0,
        int* __restrict__ idxw, float* __restrict__ out2){
  __shared__ float sp[12288];
  int tid=threadIdx.x;
  int g = blockIdx.x*4 + (tid>>6);
  int lane = tid&63;
  int b = blockIdx.x>>8;
  const float* xb = xyz + (size_t)b*4096*3;
  const float4* src=(const float4*)xb; float4* dst=(float4*)sp;
  #pragma unroll
  for(int i=0;i<12;i++) dst[i*256+tid]=src[i*256+tid];
  __syncthreads();
  float cx=out0[(size_t)g*3], cy=out0[(size_t)g*3+1], cz=out0[(size_t)g*3+2];
  const float R2 = (float)(0.2*0.2);
  int cnt=0, firstp=0; bool haveFirst=false;
  for(int c=0;c<64;c++){
    int p=c*64+lane;
    float x=sp[3*p], y=sp[3*p+1], z=sp[3*p+2];
    float d2=dist2e(x,y,z,cx,cy,cz);
    bool inb = d2 < R2;
    unsigned long long mask=__ballot(inb);
    if(!haveFirst && mask){ firstp = c*64 + (__ffsll((unsigned long long)mask)-1); haveFirst=true; }
    int pos = cnt + (int)__popcll(mask & ((1ull<<lane)-1ull));
    if(inb && pos<32){ idxw[(size_t)g*32+pos]=p; out2[(size_t)g*32+pos]=(float)p; }
    cnt += (int)__popcll(mask);
    if(cnt>=32) break;
  }
  if(cnt<32){
    for(int j=cnt+lane; j<32; j+=64){ idxw[(size_t)g*32+j]=firstp; out2[(size_t)g*32+j]=(float)firstp; }
  }
}

// ---------------- M = Wq * Wk^T  (3x128) ----------------
__global__ void m_kernel(const float* __restrict__ Wq, const float* __restrict__ Wk, float* __restrict__ M){
  int c = threadIdx.x; // 128
  float m0=0.f,m1=0.f,m2=0.f;
  for(int d=0; d<128; d++){
    float wk = Wk[c*128+d];
    m0 += Wq[d]*wk; m1 += Wq[128+d]*wk; m2 += Wq[256+d]*wk;
  }
  M[c]=m0; M[128+c]=m1; M[256+c]=m2;
}

// ---------------- layer0: gather + (67->64) matmul + bias + partial stats ----------------
__global__ __launch_bounds__(256) void l0_kernel(const float* __restrict__ xyz, const float* __restrict__ pts,
    const float* __restrict__ out0, const int* __restrict__ idxw,
    const float* __restrict__ W0, const float* __restrict__ b0,
    __hip_bfloat16* __restrict__ y0, float* __restrict__ P){
  __shared__ float xl[64*69];
  int tid=threadIdx.x; int base=blockIdx.x*64;
  int w=tid>>6, lane=tid&63;
  for(int i=0;i<16;i++){
    int r=w*16+i; int R=base+r;
    int g=R>>5; int b=g>>10; int p=idxw[R];
    const float* prow = pts + ((size_t)b*4096 + (size_t)p)*64;
    xl[r*69+3+lane] = prow[lane];
    if(lane<3){
      xl[r*69+lane] = fsubr(xyz[((size_t)b*4096+(size_t)p)*3+lane], out0[(size_t)g*3+lane]);
    }
  }
  __syncthreads();
  int r=tid&63;
  int cgu=__builtin_amdgcn_readfirstlane(tid>>6);
  float acc[16];
  #pragma unroll
  for(int j=0;j<16;j++) acc[j]=b0[cgu*16+j];
  for(int c=0;c<67;c++){
    float xv=xl[r*69+c];
    #pragma unroll
    for(int j=0;j<16;j++) acc[j] += xv*W0[c*64+cgu*16+j];
  }
  size_t R=(size_t)base+r;
  unsigned short tb[16];
  #pragma unroll
  for(int j=0;j<16;j++) tb[j]=f2bf(acc[j]);
  uint4* ov=(uint4*)(y0 + R*64 + cgu*16);
  ov[0]=make_uint4(tb[0]|(tb[1]<<16), tb[2]|(tb[3]<<16), tb[4]|(tb[5]<<16), tb[6]|(tb[7]<<16));
  ov[1]=make_uint4(tb[8]|(tb[9]<<16), tb[10]|(tb[11]<<16), tb[12]|(tb[13]<<16), tb[14]|(tb[15]<<16));
  #pragma unroll
  for(int j=0;j<16;j++){
    float s=acc[j], q=acc[j]*acc[j];
    #pragma unroll
    for(int m=32;m>=1;m>>=1){ s+=__shfl_xor(s,m); q+=__shfl_xor(q,m); }
    if(r==0){ P[(size_t)(cgu*16+j)*4096 + blockIdx.x]=s; P[(size_t)(128+cgu*16+j)*4096 + blockIdx.x]=q; }
  }
}

// ---------------- mid layers: bn(prev)+relu on load, matmul, bias, partial stats ----------------
template<int CIN,int COUT>
__global__ __launch_bounds__(256) void lmid_kernel(const __hip_bfloat16* __restrict__ xin,
    const float* __restrict__ ssIn, const float* __restrict__ W, const float* __restrict__ bias,
    __hip_bfloat16* __restrict__ yout, float* __restrict__ P){
  constexpr int STR=CIN+1;
  constexpr int PER=COUT/4;
  __shared__ float xl[64*STR];
  int tid=threadIdx.x; size_t base=(size_t)blockIdx.x*64;
  constexpr int CHUNKS = 64*CIN/8;
  #pragma unroll
  for(int i=0;i<CHUNKS/256;i++){
    int e=i*256+tid;
    int r=e/(CIN/8), c0=(e%(CIN/8))*8;
    uint4 raw = *reinterpret_cast<const uint4*>(xin + (base+(size_t)r)*CIN + c0);
    unsigned u[4]={raw.x,raw.y,raw.z,raw.w};
    #pragma unroll
    for(int k=0;k<4;k++){
      int c=c0+2*k;
      float lo=__uint_as_float(u[k]<<16);
      float hi=__uint_as_float(u[k]&0xFFFF0000u);
      float a=lo*ssIn[c]+ssIn[128+c];
      float bq=hi*ssIn[c+1]+ssIn[128+c+1];
      xl[r*STR+c]  = a>0.f?a:0.f;
      xl[r*STR+c+1]= bq>0.f?bq:0.f;
    }
  }
  __syncthreads();
  int r=tid&63;
  int cgu=__builtin_amdgcn_readfirstlane(tid>>6);
  float acc[PER];
  #pragma unroll
  for(int j=0;j<PER;j++) acc[j]=bias[cgu*PER+j];
  for(int c=0;c<CIN;c++){
    float xv=xl[r*STR+c];
    #pragma unroll
    for(int j=0;j<PER;j++) acc[j] += xv*W[c*COUT+cgu*PER+j];
  }
  size_t R=base+r;
  unsigned short tb[PER];
  #pragma unroll
  for(int j=0;j<PER;j++) tb[j]=f2bf(acc[j]);
  uint4* ov=(uint4*)(yout + R*COUT + cgu*PER);
  #pragma unroll
  for(int v=0;v<PER/8;v++)
    ov[v]=make_uint4(tb[v*8]|(tb[v*8+1]<<16), tb[v*8+2]|(tb[v*8+3]<<16), tb[v*8+4]|(tb[v*8+5]<<16), tb[v*8+6]|(tb[v*8+7]<<16));
  #pragma unroll
  for(int j=0;j<PER;j++){
    float s=acc[j],q=acc[j]*acc[j];
    #pragma unroll
    for(int m=32;m>=1;m>>=1){s+=__shfl_xor(s,m);q+=__shfl_xor(q,m);}
    if(r==0){ P[(size_t)(cgu*PER+j)*4096 + blockIdx.x]=s; P[(size_t)(128+cgu*PER+j)*4096 + blockIdx.x]=q; }
  }
}

// ---------------- finalize stats: scale/shift per channel ----------------
__global__ void fin_kernel(const float* __restrict__ P, const float* __restrict__ gg, const float* __restrict__ be,
                           float* __restrict__ ss){
  int ch=blockIdx.x; int lane=threadIdx.x;
  float s=0.f,q=0.f;
  for(int blk=lane; blk<4096; blk+=64){ s+=P[(size_t)ch*4096+blk]; q+=P[(size_t)(128+ch)*4096+blk]; }
  #pragma unroll
  for(int m=32;m>=1;m>>=1){ s+=__shfl_xor(s,m); q+=__shfl_xor(q,m); }
  if(lane==0){
    const float invNT = 1.0f/262144.0f;
    float mean=s*invNT; float var=q*invNT - mean*mean;
    float scale=gg[ch]/sqrtf(var+1e-3f);
    ss[ch]=scale; ss[128+ch]=be[ch]-mean*scale;
  }
}

// ---------------- per-group: bn2+relu, u=center@M, scores, softmax, hbar ----------------
__global__ __launch_bounds__(256) void sh_kernel(const __hip_bfloat16* __restrict__ y2,
    const float* __restrict__ ss2, const float* __restrict__ M, const float* __restrict__ out0,
    float* __restrict__ hbar){
  __shared__ float h[2][32*130];
  __shared__ float uLds[2][128];
  __shared__ float sLds[2][32];
  int tid=threadIdx.x; int grp=tid>>7, t=tid&127;
  size_t g=(size_t)blockIdx.x*2+grp;
  #pragma unroll
  for(int i=0;i<4;i++){
    int e=i*128+t;
    int row=e>>4, c0=(e&15)*8;
    uint4 raw=*reinterpret_cast<const uint4*>(y2+(g*32+(size_t)row)*128+c0);
    unsigned u[4]={raw.x,raw.y,raw.z,raw.w};
    #pragma unroll
    for(int k=0;k<4;k++){
      int c=c0+2*k;
      float lo=__uint_as_float(u[k]<<16), hi=__uint_as_float(u[k]&0xFFFF0000u);
      float a=lo*ss2[c]+ss2[128+c]; float bq=hi*ss2[c+1]+ss2[128+c+1];
      h[grp][row*130+c]  = a>0.f?a:0.f;
      h[grp][row*130+c+1]= bq>0.f?bq:0.f;
    }
  }
  float cx=out0[g*3], cy=out0[g*3+1], cz=out0[g*3+2];
  uLds[grp][t]=cx*M[t]+cy*M[128+t]+cz*M[256+t];
  __syncthreads();
  if(t<32){
    float sc=0.f;
    for(int c=0;c<128;c++) sc+=h[grp][t*130+c]*uLds[grp][c];
    sc*=0.08838834764831845f; // 1/sqrt(128)
    float mx=sc;
    #pragma unroll
    for(int m=16;m>=1;m>>=1) mx=fmaxf(mx,__shfl_xor(mx,m));
    float p=expf(sc-mx);
    float sum=p;
    #pragma unroll
    for(int m=16;m>=1;m>>=1) sum+=__shfl_xor(sum,m);
    sLds[grp][t]=p/sum;
  }
  __syncthreads();
  float hb=0.f;
  for(int k=0;k<32;k++) hb+=sLds[grp][k]*h[grp][k*130+t];
  hbar[g*128+t]=hb;
}

// ---------------- pooled = hbar @ Wv ----------------
__global__ __launch_bounds__(256) void pool_kernel(const float* __restrict__ hbar, const float* __restrict__ Wv,
    float* __restrict__ out1){
  __shared__ float xl[32*129];
  int tid=threadIdx.x; size_t g0=(size_t)blockIdx.x*32;
  for(int e=tid;e<32*128;e+=256){ int r=e>>7,ch=e&127; xl[r*129+ch]=hbar[(g0+(size_t)r)*128+ch]; }
  __syncthreads();
  int r=tid&31;
  int cgu=__builtin_amdgcn_readfirstlane(tid>>5);
  float acc[16];
  #pragma unroll
  for(int j=0;j<16;j++) acc[j]=0.f;
  for(int c=0;c<128;c++){
    float xv=xl[r*129+c];
    #pragma unroll
    for(int j=0;j<16;j++) acc[j]+=xv*Wv[c*128+cgu*16+j];
  }
  #pragma unroll
  for(int j=0;j<16;j++) out1[(g0+(size_t)r)*128+cgu*16+j]=acc[j];
}

extern "C" void kernel_launch(void* const* d_in, const int* in_sizes, int n_in,
                              void* d_out, int out_size, void* d_ws, size_t ws_size,
                              hipStream_t stream){
  (void)in_sizes; (void)n_in; (void)out_size; (void)ws_size;
  const float* xyz=(const float*)d_in[0];
  const float* pts=(const float*)d_in[1];
  const float* W0=(const float*)d_in[2];  const float* b0=(const float*)d_in[3];
  const float* g0=(const float*)d_in[4];  const float* be0=(const float*)d_in[5];
  const float* W1=(const float*)d_in[6];  const float* b1=(const float*)d_in[7];
  const float* g1=(const float*)d_in[8];  const float* be1=(const float*)d_in[9];
  const float* W2=(const float*)d_in[10]; const float* b2=(const float*)d_in[11];
  const float* g2=(const float*)d_in[12]; const float* be2=(const float*)d_in[13];
  const float* Wq=(const float*)d_in[14]; const float* Wk=(const float*)d_in[15];
  const float* Wv=(const float*)d_in[16];
  float* out0=(float*)d_out;
  float* out1=out0 + (size_t)8*1024*3;
  float* out2=out1 + (size_t)8192*128;

  char* ws=(char*)d_ws; size_t off=0;
  int* idxw=(int*)(ws+off);                    off += (size_t)8192*32*4;
  __hip_bfloat16* fa=(__hip_bfloat16*)(ws+off); off += (size_t)262144*64*2;
  __hip_bfloat16* fb=(__hip_bfloat16*)(ws+off); off += (size_t)262144*64*2;
  __hip_bfloat16* fc=(__hip_bfloat16*)(ws+off); off += (size_t)262144*128*2;
  float* P =(float*)(ws+off);                  off += (size_t)256*4096*4;
  float* ss0=(float*)(ws+off);                 off += 256*4;
  float* ss1=(float*)(ws+off);                 off += 256*4;
  float* ss2=(float*)(ws+off);                 off += 256*4;
  float* M =(float*)(ws+off);                  off += 3*128*4 + 128;
  float* hb=(float*)(ws+off);                  off += (size_t)8192*128*4;

  hipLaunchKernelGGL(fps_kernel,   dim3(8),    dim3(512),  0, stream, xyz, out0);
  hipLaunchKernelGGL(ballq_kernel, dim3(2048), dim3(256),  0, stream, xyz, out0, idxw, out2);
  hipLaunchKernelGGL(m_kernel,     dim3(1),    dim3(128),  0, stream, Wq, Wk, M);
  hipLaunchKernelGGL(l0_kernel,    dim3(4096), dim3(256),  0, stream, xyz, pts, out0, idxw, W0, b0, fa, P);
  hipLaunchKernelGGL(fin_kernel,   dim3(64),   dim3(64),   0, stream, P, g0, be0, ss0);
  hipLaunchKernelGGL((lmid_kernel<64,64>),  dim3(4096), dim3(256), 0, stream, fa, ss0, W1, b1, fb, P);
  hipLaunchKernelGGL(fin_kernel,   dim3(64),   dim3(64),   0, stream, P, g1, be1, ss1);
  hipLaunchKernelGGL((lmid_kernel<64,128>), dim3(4096), dim3(256), 0, stream, fb, ss1, W2, b2, fc, P);
  hipLaunchKernelGGL(fin_kernel,   dim3(128),  dim3(64),   0, stream, P, g2, be2, ss2);
  hipLaunchKernelGGL(sh_kernel,    dim3(4096), dim3(256),  0, stream, fc, ss2, M, out0, hb);
  hipLaunchKernelGGL(pool_kernel,  dim3(256),  dim3(256),  0, stream, hb, Wv, out1);
}

// Round 3
// 1089.212 us; speedup vs baseline: 1.7884x; 1.2913x over previous
//
#include <hip/hip_runtime.h>
#include <hip/hip_bf16.h>

#define DI __device__ __forceinline__

DI float fmulr(float a, float b){ return __fmul_rn(a,b); }
DI float faddr(float a, float b){ return __fadd_rn(a,b); }
DI float fsubr(float a, float b){ return __fsub_rn(a,b); }
DI float dist2e(float x,float y,float z,float cx,float cy,float cz){
  float dx=fsubr(x,cx), dy=fsubr(y,cy), dz=fsubr(z,cz);
  return faddr(faddr(fmulr(dx,dx),fmulr(dy,dy)),fmulr(dz,dz));
}
DI unsigned short f2bf(float f){ __hip_bfloat16 h=__float2bfloat16(f); return *reinterpret_cast<unsigned short*>(&h); }

// ---------------- FPS: 8 blocks (one per batch), 256 threads, 16 pts/lane ----------------
// Point ownership is CONSECUTIVE per lane (p = tid*16 + j) so index order is
// monotone in (wave, lane, j). Tie-break "first occurrence" therefore reduces to
// lowest lane (ballot+ffs) within a wave; the u64 packed key handles cross-wave.
__global__ __launch_bounds__(256) void fps_kernel(const float* __restrict__ xyz, float* __restrict__ out0){
  __shared__ float sp[12288];
  __shared__ unsigned long long slots[2][4];
  int b=blockIdx.x, tid=threadIdx.x;
  const float* xb = xyz + (size_t)b*4096*3;
  const float4* src=(const float4*)xb; float4* dst=(float4*)sp;
  #pragma unroll
  for(int i=0;i<12;i++) dst[i*256+tid]=src[i*256+tid];
  __syncthreads();
  float px[16],py[16],pz[16],dist[16];
  int p0 = tid*16;
  #pragma unroll
  for(int j=0;j<16;j++){ px[j]=sp[3*(p0+j)]; py[j]=sp[3*(p0+j)+1]; pz[j]=sp[3*(p0+j)+2]; dist[j]=1e10f; }
  float cx=sp[0], cy=sp[1], cz=sp[2];
  int w=tid>>6, lane=tid&63;
  float* ob = out0 + (size_t)b*1024*3;
  #pragma unroll 1
  for(int t=0;t<1024;t++){
    if(tid==0){ ob[t*3]=cx; ob[t*3+1]=cy; ob[t*3+2]=cz; }
    float bv=-1.0f; int bj=0;
    #pragma unroll
    for(int j=0;j<16;j++){
      float d=dist2e(px[j],py[j],pz[j],cx,cy,cz);
      float nd=fminf(dist[j],d); dist[j]=nd;
      bj = (nd>bv)? j : bj;      // strict > keeps first occurrence (lowest j)
      bv = fmaxf(bv,nd);
    }
    int bi = p0 + bj;
    // value-only wave butterfly (shorter dependence chain than (v,i) pairs)
    float wv = bv;
    #pragma unroll
    for(int m=32;m>=1;m>>=1) wv = fmaxf(wv, __shfl_xor(wv,m));
    unsigned long long mask = __ballot(bv==wv);
    int L = (int)(__ffsll((unsigned long long)mask)-1);  // lowest lane == lowest index range
    int wbi = __shfl(bi, L);
    if(lane==0) slots[t&1][w] = ((unsigned long long)__float_as_uint(wv)<<32)
                              | (unsigned long long)(0xFFFFFFFFu-(unsigned)wbi);
    __syncthreads();
    unsigned long long k = slots[t&1][0];
    #pragma unroll
    for(int j=1;j<4;j++){ unsigned long long ok=slots[t&1][j]; if(ok>k) k=ok; }
    int cur = (int)(0xFFFFFFFFu - (unsigned)(k & 0xFFFFFFFFull));
    cx=sp[3*cur]; cy=sp[3*cur+1]; cz=sp[3*cur+2];
  }
}

// ---------------- ball query: 4 waves/block share one batch staged in LDS ----------------
__global__ __launch_bounds__(256) void ballq_kernel(const float* __restrict__ xyz, const float* __restrict__ out0,
        int* __restrict__ idxw, float* __restrict__ out2){
  __shared__ float sp[12288];
  int tid=threadIdx.x;
  int g = blockIdx.x*4 + (tid>>6);
  int lane = tid&63;
  int b = blockIdx.x>>8;
  const float* xb = xyz + (size_t)b*4096*3;
  const float4* src=(const float4*)xb; float4* dst=(float4*)sp;
  #pragma unroll
  for(int i=0;i<12;i++) dst[i*256+tid]=src[i*256+tid];
  __syncthreads();
  float cx=out0[(size_t)g*3], cy=out0[(size_t)g*3+1], cz=out0[(size_t)g*3+2];
  const float R2 = (float)(0.2*0.2);
  int cnt=0, firstp=0; bool haveFirst=false;
  for(int c=0;c<64;c++){
    int p=c*64+lane;
    float x=sp[3*p], y=sp[3*p+1], z=sp[3*p+2];
    float d2=dist2e(x,y,z,cx,cy,cz);
    bool inb = d2 < R2;
    unsigned long long mask=__ballot(inb);
    if(!haveFirst && mask){ firstp = c*64 + (__ffsll((unsigned long long)mask)-1); haveFirst=true; }
    int pos = cnt + (int)__popcll(mask & ((1ull<<lane)-1ull));
    if(inb && pos<32){ idxw[(size_t)g*32+pos]=p; out2[(size_t)g*32+pos]=(float)p; }
    cnt += (int)__popcll(mask);
    if(cnt>=32) break;
  }
  if(cnt<32){
    for(int j=cnt+lane; j<32; j+=64){ idxw[(size_t)g*32+j]=firstp; out2[(size_t)g*32+j]=(float)firstp; }
  }
}

// ---------------- M = Wq * Wk^T  (3x128) ----------------
__global__ void m_kernel(const float* __restrict__ Wq, const float* __restrict__ Wk, float* __restrict__ M){
  int c = threadIdx.x; // 128
  float m0=0.f,m1=0.f,m2=0.f;
  for(int d=0; d<128; d++){
    float wk = Wk[c*128+d];
    m0 += Wq[d]*wk; m1 += Wq[128+d]*wk; m2 += Wq[256+d]*wk;
  }
  M[c]=m0; M[128+c]=m1; M[256+c]=m2;
}

// ---------------- layer0: gather + (67->64) matmul + bias + partial stats ----------------
__global__ __launch_bounds__(256) void l0_kernel(const float* __restrict__ xyz, const float* __restrict__ pts,
    const float* __restrict__ out0, const int* __restrict__ idxw,
    const float* __restrict__ W0, const float* __restrict__ b0,
    __hip_bfloat16* __restrict__ y0, float* __restrict__ P){
  __shared__ float xl[64*69];
  int tid=threadIdx.x; int base=blockIdx.x*64;
  int w=tid>>6, lane=tid&63;
  for(int i=0;i<16;i++){
    int r=w*16+i; int R=base+r;
    int g=R>>5; int b=g>>10; int p=idxw[R];
    const float* prow = pts + ((size_t)b*4096 + (size_t)p)*64;
    xl[r*69+3+lane] = prow[lane];
    if(lane<3){
      xl[r*69+lane] = fsubr(xyz[((size_t)b*4096+(size_t)p)*3+lane], out0[(size_t)g*3+lane]);
    }
  }
  __syncthreads();
  int r=tid&63;
  int cgu=__builtin_amdgcn_readfirstlane(tid>>6);
  float acc[16];
  #pragma unroll
  for(int j=0;j<16;j++) acc[j]=b0[cgu*16+j];
  for(int c=0;c<67;c++){
    float xv=xl[r*69+c];
    #pragma unroll
    for(int j=0;j<16;j++) acc[j] += xv*W0[c*64+cgu*16+j];
  }
  size_t R=(size_t)base+r;
  unsigned short tb[16];
  #pragma unroll
  for(int j=0;j<16;j++) tb[j]=f2bf(acc[j]);
  uint4* ov=(uint4*)(y0 + R*64 + cgu*16);
  ov[0]=make_uint4(tb[0]|(tb[1]<<16), tb[2]|(tb[3]<<16), tb[4]|(tb[5]<<16), tb[6]|(tb[7]<<16));
  ov[1]=make_uint4(tb[8]|(tb[9]<<16), tb[10]|(tb[11]<<16), tb[12]|(tb[13]<<16), tb[14]|(tb[15]<<16));
  #pragma unroll
  for(int j=0;j<16;j++){
    float s=acc[j], q=acc[j]*acc[j];
    #pragma unroll
    for(int m=32;m>=1;m>>=1){ s+=__shfl_xor(s,m); q+=__shfl_xor(q,m); }
    if(r==0){ P[(size_t)(cgu*16+j)*4096 + blockIdx.x]=s; P[(size_t)(128+cgu*16+j)*4096 + blockIdx.x]=q; }
  }
}

// ---------------- mid layers: bn(prev)+relu on load, matmul, bias, partial stats ----------------
template<int CIN,int COUT>
__global__ __launch_bounds__(256) void lmid_kernel(const __hip_bfloat16* __restrict__ xin,
    const float* __restrict__ ssIn, const float* __restrict__ W, const float* __restrict__ bias,
    __hip_bfloat16* __restrict__ yout, float* __restrict__ P){
  constexpr int STR=CIN+1;
  constexpr int PER=COUT/4;
  __shared__ float xl[64*STR];
  int tid=threadIdx.x; size_t base=(size_t)blockIdx.x*64;
  constexpr int CHUNKS = 64*CIN/8;
  #pragma unroll
  for(int i=0;i<CHUNKS/256;i++){
    int e=i*256+tid;
    int r=e/(CIN/8), c0=(e%(CIN/8))*8;
    uint4 raw = *reinterpret_cast<const uint4*>(xin + (base+(size_t)r)*CIN + c0);
    unsigned u[4]={raw.x,raw.y,raw.z,raw.w};
    #pragma unroll
    for(int k=0;k<4;k++){
      int c=c0+2*k;
      float lo=__uint_as_float(u[k]<<16);
      float hi=__uint_as_float(u[k]&0xFFFF0000u);
      float a=lo*ssIn[c]+ssIn[128+c];
      float bq=hi*ssIn[c+1]+ssIn[128+c+1];
      xl[r*STR+c]  = a>0.f?a:0.f;
      xl[r*STR+c+1]= bq>0.f?bq:0.f;
    }
  }
  __syncthreads();
  int r=tid&63;
  int cgu=__builtin_amdgcn_readfirstlane(tid>>6);
  float acc[PER];
  #pragma unroll
  for(int j=0;j<PER;j++) acc[j]=bias[cgu*PER+j];
  for(int c=0;c<CIN;c++){
    float xv=xl[r*STR+c];
    #pragma unroll
    for(int j=0;j<PER;j++) acc[j] += xv*W[c*COUT+cgu*PER+j];
  }
  size_t R=base+r;
  unsigned short tb[PER];
  #pragma unroll
  for(int j=0;j<PER;j++) tb[j]=f2bf(acc[j]);
  uint4* ov=(uint4*)(yout + R*COUT + cgu*PER);
  #pragma unroll
  for(int v=0;v<PER/8;v++)
    ov[v]=make_uint4(tb[v*8]|(tb[v*8+1]<<16), tb[v*8+2]|(tb[v*8+3]<<16), tb[v*8+4]|(tb[v*8+5]<<16), tb[v*8+6]|(tb[v*8+7]<<16));
  #pragma unroll
  for(int j=0;j<PER;j++){
    float s=acc[j],q=acc[j]*acc[j];
    #pragma unroll
    for(int m=32;m>=1;m>>=1){s+=__shfl_xor(s,m);q+=__shfl_xor(q,m);}
    if(r==0){ P[(size_t)(cgu*PER+j)*4096 + blockIdx.x]=s; P[(size_t)(128+cgu*PER+j)*4096 + blockIdx.x]=q; }
  }
}

// ---------------- finalize stats: scale/shift per channel ----------------
__global__ void fin_kernel(const float* __restrict__ P, const float* __restrict__ gg, const float* __restrict__ be,
                           float* __restrict__ ss){
  int ch=blockIdx.x; int lane=threadIdx.x;
  float s=0.f,q=0.f;
  for(int blk=lane; blk<4096; blk+=64){ s+=P[(size_t)ch*4096+blk]; q+=P[(size_t)(128+ch)*4096+blk]; }
  #pragma unroll
  for(int m=32;m>=1;m>>=1){ s+=__shfl_xor(s,m); q+=__shfl_xor(q,m); }
  if(lane==0){
    const float invNT = 1.0f/262144.0f;
    float mean=s*invNT; float var=q*invNT - mean*mean;
    float scale=gg[ch]/sqrtf(var+1e-3f);
    ss[ch]=scale; ss[128+ch]=be[ch]-mean*scale;
  }
}

// ---------------- per-group: bn2+relu, u=center@M, scores, softmax, hbar ----------------
__global__ __launch_bounds__(256) void sh_kernel(const __hip_bfloat16* __restrict__ y2,
    const float* __restrict__ ss2, const float* __restrict__ M, const float* __restrict__ out0,
    float* __restrict__ hbar){
  __shared__ float h[2][32*130];
  __shared__ float uLds[2][128];
  __shared__ float sLds[2][32];
  int tid=threadIdx.x; int grp=tid>>7, t=tid&127;
  size_t g=(size_t)blockIdx.x*2+grp;
  #pragma unroll
  for(int i=0;i<4;i++){
    int e=i*128+t;
    int row=e>>4, c0=(e&15)*8;
    uint4 raw=*reinterpret_cast<const uint4*>(y2+(g*32+(size_t)row)*128+c0);
    unsigned u[4]={raw.x,raw.y,raw.z,raw.w};
    #pragma unroll
    for(int k=0;k<4;k++){
      int c=c0+2*k;
      float lo=__uint_as_float(u[k]<<16), hi=__uint_as_float(u[k]&0xFFFF0000u);
      float a=lo*ss2[c]+ss2[128+c]; float bq=hi*ss2[c+1]+ss2[128+c+1];
      h[grp][row*130+c]  = a>0.f?a:0.f;
      h[grp][row*130+c+1]= bq>0.f?bq:0.f;
    }
  }
  float cx=out0[g*3], cy=out0[g*3+1], cz=out0[g*3+2];
  uLds[grp][t]=cx*M[t]+cy*M[128+t]+cz*M[256+t];
  __syncthreads();
  if(t<32){
    float sc=0.f;
    for(int c=0;c<128;c++) sc+=h[grp][t*130+c]*uLds[grp][c];
    sc*=0.08838834764831845f; // 1/sqrt(128)
    float mx=sc;
    #pragma unroll
    for(int m=16;m>=1;m>>=1) mx=fmaxf(mx,__shfl_xor(mx,m));
    float p=expf(sc-mx);
    float sum=p;
    #pragma unroll
    for(int m=16;m>=1;m>>=1) sum+=__shfl_xor(sum,m);
    sLds[grp][t]=p/sum;
  }
  __syncthreads();
  float hb=0.f;
  for(int k=0;k<32;k++) hb+=sLds[grp][k]*h[grp][k*130+t];
  hbar[g*128+t]=hb;
}

// ---------------- pooled = hbar @ Wv ----------------
__global__ __launch_bounds__(256) void pool_kernel(const float* __restrict__ hbar, const float* __restrict__ Wv,
    float* __restrict__ out1){
  __shared__ float xl[32*129];
  int tid=threadIdx.x; size_t g0=(size_t)blockIdx.x*32;
  for(int e=tid;e<32*128;e+=256){ int r=e>>7,ch=e&127; xl[r*129+ch]=hbar[(g0+(size_t)r)*128+ch]; }
  __syncthreads();
  int r=tid&31;
  int cgu=__builtin_amdgcn_readfirstlane(tid>>5);
  float acc[16];
  #pragma unroll
  for(int j=0;j<16;j++) acc[j]=0.f;
  for(int c=0;c<128;c++){
    float xv=xl[r*129+c];
    #pragma unroll
    for(int j=0;j<16;j++) acc[j]+=xv*Wv[c*128+cgu*16+j];
  }
  #pragma unroll
  for(int j=0;j<16;j++) out1[(g0+(size_t)r)*128+cgu*16+j]=acc[j];
}

extern "C" void kernel_launch(void* const* d_in, const int* in_sizes, int n_in,
                              void* d_out, int out_size, void* d_ws, size_t ws_size,
                              hipStream_t stream){
  (void)in_sizes; (void)n_in; (void)out_size; (void)ws_size;
  const float* xyz=(const float*)d_in[0];
  const float* pts=(const float*)d_in[1];
  const float* W0=(const float*)d_in[2];  const float* b0=(const float*)d_in[3];
  const float* g0=(const float*)d_in[4];  const float* be0=(const float*)d_in[5];
  const float* W1=(const float*)d_in[6];  const float* b1=(const float*)d_in[7];
  const float* g1=(const float*)d_in[8];  const float* be1=(const float*)d_in[9];
  const float* W2=(const float*)d_in[10]; const float* b2=(const float*)d_in[11];
  const float* g2=(const float*)d_in[12]; const float* be2=(const float*)d_in[13];
  const float* Wq=(const float*)d_in[14]; const float* Wk=(const float*)d_in[15];
  const float* Wv=(const float*)d_in[16];
  float* out0=(float*)d_out;
  float* out1=out0 + (size_t)8*1024*3;
  float* out2=out1 + (size_t)8192*128;

  char* ws=(char*)d_ws; size_t off=0;
  int* idxw=(int*)(ws+off);                    off += (size_t)8192*32*4;
  __hip_bfloat16* fa=(__hip_bfloat16*)(ws+off); off += (size_t)262144*64*2;
  __hip_bfloat16* fb=(__hip_bfloat16*)(ws+off); off += (size_t)262144*64*2;
  __hip_bfloat16* fc=(__hip_bfloat16*)(ws+off); off += (size_t)262144*128*2;
  float* P =(float*)(ws+off);                  off += (size_t)256*4096*4;
  float* ss0=(float*)(ws+off);                 off += 256*4;
  float* ss1=(float*)(ws+off);                 off += 256*4;
  float* ss2=(float*)(ws+off);                 off += 256*4;
  float* M =(float*)(ws+off);                  off += 3*128*4 + 128;
  float* hb=(float*)(ws+off);                  off += (size_t)8192*128*4;

  hipLaunchKernelGGL(fps_kernel,   dim3(8),    dim3(256),  0, stream, xyz, out0);
  hipLaunchKernelGGL(ballq_kernel, dim3(2048), dim3(256),  0, stream, xyz, out0, idxw, out2);
  hipLaunchKernelGGL(m_kernel,     dim3(1),    dim3(128),  0, stream, Wq, Wk, M);
  hipLaunchKernelGGL(l0_kernel,    dim3(4096), dim3(256),  0, stream, xyz, pts, out0, idxw, W0, b0, fa, P);
  hipLaunchKernelGGL(fin_kernel,   dim3(64),   dim3(64),   0, stream, P, g0, be0, ss0);
  hipLaunchKernelGGL((lmid_kernel<64,64>),  dim3(4096), dim3(256), 0, stream, fa, ss0, W1, b1, fb, P);
  hipLaunchKernelGGL(fin_kernel,   dim3(64),   dim3(64),   0, stream, P, g1, be1, ss1);
  hipLaunchKernelGGL((lmid_kernel<64,128>), dim3(4096), dim3(256), 0, stream, fb, ss1, W2, b2, fc, P);
  hipLaunchKernelGGL(fin_kernel,   dim3(128),  dim3(64),   0, stream, P, g2, be2, ss2);
  hipLaunchKernelGGL(sh_kernel,    dim3(4096), dim3(256),  0, stream, fc, ss2, M, out0, hb);
  hipLaunchKernelGGL(pool_kernel,  dim3(256),  dim3(256),  0, stream, hb, Wv, out1);
}